// Round 3
// baseline (546.064 us; speedup 1.0000x reference)
//
#include <hip/hip_runtime.h>

#define DIM 64
#define UNR 8   // slots per iter; 4 tokens/slot => 32 tokens (8 KB) in flight per wave

static __device__ __forceinline__ int lower_bound(const int* __restrict__ a, int n, int v) {
    int lo = 0, hi = n;
    while (lo < hi) {
        int m = (lo + hi) >> 1;
        if (a[m] < v) lo = m + 1; else hi = m;
    }
    return lo;
}

// Wave layout: group g = lane>>4 (4 groups), l = lane&15.
// Group g handles token base+4*j+g; lane covers dims [4l, 4l+4) as float4.
// One global_load_dwordx4 per slot fetches 4 full 256B rows (1 KB/instr).
// Tail: clamp token index into the segment and zero the weight (no divergence;
// trip count is wave-uniform).
static __device__ __forceinline__ float4 ragged_accum4(
    const float* __restrict__ table,
    const int* __restrict__ idx, const float* __restrict__ val,
    int ts, int te, int g, int l)
{
    float4 acc = {0.f, 0.f, 0.f, 0.f};
    const int n = te - ts;
    if (n <= 0) return acc;
    const int iters = (n + 4 * UNR - 1) / (4 * UNR);
    for (int it = 0; it < iters; ++it) {
        const int base = ts + it * 4 * UNR + g;
        #pragma unroll
        for (int j = 0; j < UNR; ++j) {
            int tt  = base + 4 * j;
            int ttc = min(tt, te - 1);            // in-bounds (n>0 => te-1 >= ts >= 0)
            int   r = idx[ttc];
            float w = (tt < te) ? val[ttc] : 0.0f;
            const float4 row = *(const float4*)(table + (size_t)r * DIM + 4 * l);
            acc.x = fmaf(row.x, w, acc.x);
            acc.y = fmaf(row.y, w, acc.y);
            acc.z = fmaf(row.z, w, acc.z);
            acc.w = fmaf(row.w, w, acc.w);
        }
    }
    return acc;
}

static __device__ __forceinline__ void group_reduce4(float4& a) {
    // sum across the 4 groups (lanes L, L+16, L+32, L+48)
    #pragma unroll
    for (int off = 16; off < 64; off <<= 1) {
        a.x += __shfl_xor(a.x, off, 64);
        a.y += __shfl_xor(a.y, off, 64);
        a.z += __shfl_xor(a.z, off, 64);
        a.w += __shfl_xor(a.w, off, 64);
    }
}

// One wave per batch sample; 256-thread block = 4 samples.
__global__ __launch_bounds__(256) void mf_fwd_kernel(
    const int* __restrict__ user_ids, const int* __restrict__ item_ids,
    const int* __restrict__ u_idx, const float* __restrict__ u_val,
    const int* __restrict__ u_seg,
    const int* __restrict__ i_idx, const float* __restrict__ i_val,
    const int* __restrict__ i_seg,
    const float* __restrict__ user_emb, const float* __restrict__ item_emb,
    const float* __restrict__ ufeat_emb, const float* __restrict__ ifeat_emb,
    const float* __restrict__ user_bias, const float* __restrict__ item_bias,
    const float* __restrict__ global_bias,
    float* __restrict__ out,
    int batch, int Tu, int Ti)
{
    const int lane = threadIdx.x & 63;
    const int wave = threadIdx.x >> 6;
    const int g = lane >> 4;
    const int l = lane & 15;
    const int b = (blockIdx.x << 2) + wave;
    if (b >= batch) return;

    int us  = __builtin_amdgcn_readfirstlane(lower_bound(u_seg, Tu, b));
    int ue  = __builtin_amdgcn_readfirstlane(lower_bound(u_seg, Tu, b + 1));
    int is0 = __builtin_amdgcn_readfirstlane(lower_bound(i_seg, Ti, b));
    int ie  = __builtin_amdgcn_readfirstlane(lower_bound(i_seg, Ti, b + 1));

    const int uid = user_ids[b];
    const int iid = item_ids[b];

    // Dense rows: 16B per lane; groups duplicate the same 16 distinct float4s
    // (hardware merges; L1 serves the duplicates).
    const float4 u0 = *(const float4*)(user_emb + (size_t)uid * DIM + 4 * l);
    const float4 v0 = *(const float4*)(item_emb + (size_t)iid * DIM + 4 * l);

    float4 ua = ragged_accum4(ufeat_emb, u_idx, u_val, us,  ue, g, l);
    float4 va = ragged_accum4(ifeat_emb, i_idx, i_val, is0, ie, g, l);

    group_reduce4(ua);
    group_reduce4(va);

    const float ux = ua.x + u0.x, uy = ua.y + u0.y, uz = ua.z + u0.z, uw = ua.w + u0.w;
    const float vx = va.x + v0.x, vy = va.y + v0.y, vz = va.z + v0.z, vw = va.w + v0.w;

    float p = ux * vx + uy * vy + uz * vz + uw * vw;
    // all 4 groups hold identical values; reduce within a 16-lane group
    #pragma unroll
    for (int off = 1; off < 16; off <<= 1)
        p += __shfl_xor(p, off, 64);

    if (lane == 0)
        out[b] = p + user_bias[uid] + item_bias[iid] + global_bias[0];
}

extern "C" void kernel_launch(void* const* d_in, const int* in_sizes, int n_in,
                              void* d_out, int out_size, void* d_ws, size_t ws_size,
                              hipStream_t stream) {
    const int*   user_ids    = (const int*)d_in[0];
    const int*   item_ids    = (const int*)d_in[1];
    const int*   u_idx       = (const int*)d_in[2];
    const float* u_val       = (const float*)d_in[3];
    const int*   u_seg       = (const int*)d_in[4];
    const int*   i_idx       = (const int*)d_in[5];
    const float* i_val       = (const float*)d_in[6];
    const int*   i_seg       = (const int*)d_in[7];
    const float* user_emb    = (const float*)d_in[8];
    const float* item_emb    = (const float*)d_in[9];
    const float* ufeat_emb   = (const float*)d_in[10];
    const float* ifeat_emb   = (const float*)d_in[11];
    const float* user_bias   = (const float*)d_in[12];
    const float* item_bias   = (const float*)d_in[13];
    const float* global_bias = (const float*)d_in[14];
    float* out = (float*)d_out;

    const int batch = in_sizes[0];
    const int Tu    = in_sizes[2];
    const int Ti    = in_sizes[5];

    const int blocks = (batch + 3) / 4;
    mf_fwd_kernel<<<blocks, 256, 0, stream>>>(
        user_ids, item_ids, u_idx, u_val, u_seg, i_idx, i_val, i_seg,
        user_emb, item_emb, ufeat_emb, ifeat_emb, user_bias, item_bias,
        global_bias, out, batch, Tu, Ti);
}

// Round 4
// 485.642 us; speedup vs baseline: 1.1244x; 1.1244x over previous
//
#include <hip/hip_runtime.h>

#define DIM 64
#define NB 16   // tokens in flight per wave per pipeline stage

// Build CSR-style offsets from a sorted segment-id array.
// off[b] = first t with seg[t] >= b, for b in [0, B]; off[B] = T.
__global__ __launch_bounds__(256) void build_offsets_kernel(
    const int* __restrict__ seg, int T, int B, int* __restrict__ off)
{
    int t = blockIdx.x * blockDim.x + threadIdx.x;
    if (t > T) return;
    int cur  = (t == T) ? B : seg[t];
    int prev = (t == 0) ? -1 : seg[t - 1];
    for (int b = prev + 1; b <= cur; ++b) off[b] = t;
}

// Weighted segment-sum over [ts, te). Wave-uniform trip count; idx/val are
// wave-uniform (scalar) loads, prefetched one batch ahead so SMEM latency
// hides under the row-gather VMEM latency. Tail tokens clamp to te-1 with
// zero weight (duplicate addresses merge in L1/L2; no divergence).
static __device__ __forceinline__ float ragged_pipelined(
    const float* __restrict__ table, const int* __restrict__ idx,
    const float* __restrict__ val, int ts, int te, int lane)
{
    float acc = 0.f;
    const int n = te - ts;
    if (n <= 0) return acc;
    const int iters = (n + NB - 1) / NB;

    int r[NB]; float w[NB];
    #pragma unroll
    for (int j = 0; j < NB; ++j) {
        int tt = ts + j, tc = min(tt, te - 1);
        r[j] = idx[tc];
        w[j] = (tt < te) ? val[tc] : 0.f;
    }

    for (int it = 0; it < iters; ++it) {
        float row[NB];
        #pragma unroll
        for (int j = 0; j < NB; ++j)
            row[j] = table[(size_t)r[j] * DIM + lane];   // NB gathers in flight

        const bool more = (it + 1 < iters);
        const int nb = ts + (it + 1) * NB;
        int r2[NB]; float w2[NB];
        if (more) {
            #pragma unroll
            for (int j = 0; j < NB; ++j) {               // prefetch under VMEM shadow
                int tt = nb + j, tc = min(tt, te - 1);
                r2[j] = idx[tc];
                w2[j] = (tt < te) ? val[tc] : 0.f;
            }
        }

        #pragma unroll
        for (int j = 0; j < NB; ++j)
            acc = fmaf(row[j], w[j], acc);

        if (more) {
            #pragma unroll
            for (int j = 0; j < NB; ++j) { r[j] = r2[j]; w[j] = w2[j]; }
        }
    }
    return acc;
}

// One wave (64 lanes = 64 dims) per batch sample; 256-thread block = 4 samples.
__global__ __launch_bounds__(256) void mf_fwd_kernel(
    const int* __restrict__ user_ids, const int* __restrict__ item_ids,
    const int* __restrict__ u_idx, const float* __restrict__ u_val,
    const int* __restrict__ i_idx, const float* __restrict__ i_val,
    const int* __restrict__ u_off, const int* __restrict__ i_off,
    const float* __restrict__ user_emb, const float* __restrict__ item_emb,
    const float* __restrict__ ufeat_emb, const float* __restrict__ ifeat_emb,
    const float* __restrict__ user_bias, const float* __restrict__ item_bias,
    const float* __restrict__ global_bias,
    float* __restrict__ out, int batch)
{
    const int lane = threadIdx.x & 63;
    const int wave = threadIdx.x >> 6;
    const int b = (blockIdx.x << 2) + wave;
    if (b >= batch) return;

    // Direct offset lookups (replaces 4 serial binary searches).
    const int us  = __builtin_amdgcn_readfirstlane(u_off[b]);
    const int ue  = __builtin_amdgcn_readfirstlane(u_off[b + 1]);
    const int is0 = __builtin_amdgcn_readfirstlane(i_off[b]);
    const int ie  = __builtin_amdgcn_readfirstlane(i_off[b + 1]);

    const int uid = user_ids[b];
    const int iid = item_ids[b];

    // Dense rows issued up front, independent of the token loops.
    const float u0 = user_emb[(size_t)uid * DIM + lane];
    const float v0 = item_emb[(size_t)iid * DIM + lane];

    const float u = u0 + ragged_pipelined(ufeat_emb, u_idx, u_val, us,  ue, lane);
    const float v = v0 + ragged_pipelined(ifeat_emb, i_idx, i_val, is0, ie, lane);

    float p = u * v;
    #pragma unroll
    for (int off = 32; off > 0; off >>= 1)
        p += __shfl_xor(p, off, 64);

    if (lane == 0)
        out[b] = p + user_bias[uid] + item_bias[iid] + global_bias[0];
}

extern "C" void kernel_launch(void* const* d_in, const int* in_sizes, int n_in,
                              void* d_out, int out_size, void* d_ws, size_t ws_size,
                              hipStream_t stream) {
    const int*   user_ids    = (const int*)d_in[0];
    const int*   item_ids    = (const int*)d_in[1];
    const int*   u_idx       = (const int*)d_in[2];
    const float* u_val       = (const float*)d_in[3];
    const int*   u_seg       = (const int*)d_in[4];
    const int*   i_idx       = (const int*)d_in[5];
    const float* i_val       = (const float*)d_in[6];
    const int*   i_seg       = (const int*)d_in[7];
    const float* user_emb    = (const float*)d_in[8];
    const float* item_emb    = (const float*)d_in[9];
    const float* ufeat_emb   = (const float*)d_in[10];
    const float* ifeat_emb   = (const float*)d_in[11];
    const float* user_bias   = (const float*)d_in[12];
    const float* item_bias   = (const float*)d_in[13];
    const float* global_bias = (const float*)d_in[14];
    float* out = (float*)d_out;

    const int batch = in_sizes[0];
    const int Tu    = in_sizes[2];
    const int Ti    = in_sizes[5];

    int* u_off = (int*)d_ws;               // batch+1 ints
    int* i_off = u_off + (batch + 1);      // batch+1 ints

    build_offsets_kernel<<<(Tu + 256) / 256 + 1, 256, 0, stream>>>(u_seg, Tu, batch, u_off);
    build_offsets_kernel<<<(Ti + 256) / 256 + 1, 256, 0, stream>>>(i_seg, Ti, batch, i_off);

    const int blocks = (batch + 3) / 4;
    mf_fwd_kernel<<<blocks, 256, 0, stream>>>(
        user_ids, item_ids, u_idx, u_val, i_idx, i_val, u_off, i_off,
        user_emb, item_emb, ufeat_emb, ifeat_emb, user_bias, item_bias,
        global_bias, out, batch);
}